// Round 5
// baseline (136.230 us; speedup 1.0000x reference)
//
#include <hip/hip_runtime.h>
#include <hip/hip_bf16.h>

typedef __bf16 bf16_t;
typedef __attribute__((ext_vector_type(4))) __bf16 bf16x4;
typedef __attribute__((ext_vector_type(8))) __bf16 bf16x8;
typedef __attribute__((ext_vector_type(4))) float f32x4;

#define MFMA16(a, b, c) __builtin_amdgcn_mfma_f32_16x16x32_bf16((a), (b), (c), 0, 0, 0)

// ---- constants ----
#define BB 16
#define SS 1024
#define DD 512
#define HH 8
#define DH 64
#define NTOK (BB * SS)          // 16384
#define QSCALE 0.18033688f      // dh^-0.5 * log2(e) folded into Q projection

typedef const __attribute__((address_space(1))) void gas_void;
typedef __attribute__((address_space(3))) void las_void;

__device__ __forceinline__ void async_cp16(const void* g, void* l) {
    __builtin_amdgcn_global_load_lds((gas_void*)g, (las_void*)l, 16, 0, 0);
}

// Load one MFMA A/B fragment (16x16x32 bf16) from a swizzled [rows][64] bf16 LDS
// tile (128 B/row, 16B chunk position = chunk ^ (row&7)).
// Element mapping: lane l, elem j -> k = 16*(j>>2) + 4*(l>>4) + (j&3).
__device__ __forceinline__ bf16x8 frag_ld(const char* sm, int row, int kk, int g) {
    int r7 = row & 7;
    int base = row * 128 + ((g & 1) << 3);
    int c0 = ((kk << 2) + (g >> 1)) ^ r7;
    int c1 = ((kk << 2) + 2 + (g >> 1)) ^ r7;
    bf16x4 lo = *(const bf16x4*)(sm + base + (c0 << 4));
    bf16x4 hi = *(const bf16x4*)(sm + base + (c1 << 4));
    return __builtin_shufflevector(lo, hi, 0, 1, 2, 3, 4, 5, 6, 7);
}

// Same fragment read with precomputed swizzled offsets (row-block via pointer).
__device__ __forceinline__ bf16x8 frag_at(const char* smrow, int a0, int a1) {
    bf16x4 lo = *(const bf16x4*)(smrow + a0);
    bf16x4 hi = *(const bf16x4*)(smrow + a1);
    return __builtin_shufflevector(lo, hi, 0, 1, 2, 3, 4, 5, 6, 7);
}

// ---------------- cast x -> bf16 ----------------
__global__ __launch_bounds__(256) void cast_x_k(const float* __restrict__ x,
                                                bf16_t* __restrict__ xb, int n4) {
    int i = blockIdx.x * 256 + threadIdx.x;
    if (i < n4) {
        float4 v = ((const float4*)x)[i];
        bf16x4 o;
        o[0] = (bf16_t)v.x; o[1] = (bf16_t)v.y; o[2] = (bf16_t)v.z; o[3] = (bf16_t)v.w;
        *(bf16x4*)(xb + (size_t)i * 4) = o;
    }
}

// ---------------- transpose + cast weights: Wt[n][k] = W[k][n] ----------------
__global__ __launch_bounds__(256) void transpose_w_k(const float* __restrict__ W0,
                                                     const float* __restrict__ W1,
                                                     const float* __restrict__ W2,
                                                     const float* __restrict__ W3,
                                                     bf16_t* __restrict__ Wt) {
    __shared__ float t[32][33];
    int z = blockIdx.z;
    const float* W = (z == 0) ? W0 : (z == 1) ? W1 : (z == 2) ? W2 : W3;
    bf16_t* out = Wt + (size_t)z * DD * DD;
    int n0 = blockIdx.x * 32, k0 = blockIdx.y * 32;
    int tx = threadIdx.x, ty = threadIdx.y;  // (32, 8)
#pragma unroll
    for (int i = 0; i < 32; i += 8)
        t[ty + i][tx] = W[(size_t)(k0 + ty + i) * DD + n0 + tx];
    __syncthreads();
#pragma unroll
    for (int i = 0; i < 32; i += 8)
        out[(size_t)(n0 + ty + i) * DD + k0 + tx] = (bf16_t)t[tx][ty + i];
}

// ---------------- work-queue builder (1 wave) ----------------
// items: active (b,h,qt) tiles, batches ordered by len DESC; within a batch
// h-major (same (b,h) adjacent -> concurrent blocks share K/V in L2).
// meta[0] = count, meta[1] = cursor (reset to 0 each launch -> deterministic).
__global__ void build_q_k(const int* __restrict__ sl, ushort* __restrict__ items,
                          int* __restrict__ meta) {
    int l = threadIdx.x;
    __shared__ int s_b[BB], s_cnt[BB], s_start[BB];
    if (l < BB) {
        int len = sl[l];
        int rank = 0;
        for (int j = 0; j < BB; ++j) {
            int lj = sl[j];
            if (lj > len || (lj == len && j < l)) ++rank;
        }
        s_b[rank] = l;
        s_cnt[rank] = ((len + 127) >> 7) * HH;
    }
    __syncthreads();
    if (l < BB) {
        int st = 0;
        for (int j = 0; j < l; ++j) st += s_cnt[j];
        s_start[l] = st;
        if (l == BB - 1) { meta[0] = st + s_cnt[l]; meta[1] = 0; }
    }
    __syncthreads();
    if (l < BB) {
        int b = s_b[l], st = s_start[l], c = s_cnt[l];
        int nqt = c >> 3;
        for (int i = 0; i < c; ++i) {
            int h = i / nqt, qt = i - h * nqt;
            items[st + i] = (ushort)((((b << 3) | h) << 3) | qt);
        }
    }
}

// ---------------- GEMM: C[M,512] = A[M,512] * W (given W^T[n][k]) ----------------
// MODE 0: grid.z selects Q(0)/K(1)/V(2); Q,K stored [bh][s][dh] bf16 (Q scaled by
//         QSCALE), V stored transposed [bh][dh][s] bf16.
// MODE 2: O projection, fp32 out + bias + query mask.
template <int MODE>
__global__ __launch_bounds__(256) void gemm_k(const bf16_t* __restrict__ A,
                                              const bf16_t* __restrict__ WtBase,
                                              bf16_t* __restrict__ oQ,
                                              bf16_t* __restrict__ oK,
                                              bf16_t* __restrict__ oVt,
                                              float* __restrict__ oO,
                                              const float* __restrict__ bo,
                                              const int* __restrict__ seq_lens) {
    __shared__ __align__(16) char smem[32768];
    char* smA = smem;
    char* smB = smem + 16384;
    const int tid = threadIdx.x;
    const int l = tid & 63, w = tid >> 6;
    const int lr = l & 15, g = l >> 4;
    const int bm = blockIdx.x, bn = blockIdx.y;
    const int z = (MODE == 0) ? blockIdx.z : 3;
    const bf16_t* Wt = WtBase + (size_t)z * DD * DD;
    const int row0 = bm * 128;
    const int col0 = bn * 128;
    const int wm = (w >> 1) * 64, wn = (w & 1) * 64;

    f32x4 acc[4][4] = {};

    for (int kt = 0; kt < 8; ++kt) {
        const int k0 = kt * 64;
        __syncthreads();
#pragma unroll
        for (int it = 0; it < 4; ++it) {
            int cl = it * 256 + tid;
            int m = cl >> 3, p = cl & 7, c = p ^ (m & 7);
            async_cp16(A + (size_t)(row0 + m) * DD + k0 + c * 8, smA + cl * 16);
        }
#pragma unroll
        for (int it = 0; it < 4; ++it) {
            int cl = it * 256 + tid;
            int m = cl >> 3, p = cl & 7, c = p ^ (m & 7);
            async_cp16(Wt + (size_t)(col0 + m) * DD + k0 + c * 8, smB + cl * 16);
        }
        __syncthreads();
#pragma unroll
        for (int kk = 0; kk < 2; ++kk) {
            bf16x8 af[4], bfr[4];
#pragma unroll
            for (int i = 0; i < 4; ++i) af[i] = frag_ld(smA, wm + i * 16 + lr, kk, g);
#pragma unroll
            for (int j = 0; j < 4; ++j) bfr[j] = frag_ld(smB, wn + j * 16 + lr, kk, g);
#pragma unroll
            for (int i = 0; i < 4; ++i)
#pragma unroll
                for (int j = 0; j < 4; ++j)
                    acc[i][j] = MFMA16(af[i], bfr[j], acc[i][j]);
        }
    }

    if (MODE == 0) {
        if (z < 2) {
            bf16_t* outp = (z == 0) ? oQ : oK;
            const float sc = (z == 0) ? QSCALE : 1.f;
#pragma unroll
            for (int i = 0; i < 4; ++i) {
                int mrow = row0 + wm + i * 16 + g * 4;
#pragma unroll
                for (int j = 0; j < 4; ++j) {
                    int n = col0 + wn + j * 16 + lr;
                    int h = n >> 6, dh = n & 63;
#pragma unroll
                    for (int r = 0; r < 4; ++r) {
                        int m = mrow + r;
                        int b = m >> 10, s = m & 1023;
                        outp[((size_t)((b * HH + h) * SS + s)) * DH + dh] =
                            (bf16_t)(acc[i][j][r] * sc);
                    }
                }
            }
        } else {
            // V: transpose to [bh][dh][s] via LDS
            __syncthreads();
            bf16_t* tsm = (bf16_t*)smem;
#pragma unroll
            for (int i = 0; i < 4; ++i)
#pragma unroll
                for (int j = 0; j < 4; ++j)
#pragma unroll
                    for (int r = 0; r < 4; ++r)
                        tsm[(wm + i * 16 + g * 4 + r) * 128 + wn + j * 16 + lr] =
                            (bf16_t)acc[i][j][r];
            __syncthreads();
            int nloc = tid >> 1;
            int mbase = (tid & 1) * 64;
            int n = col0 + nloc;
            int h = n >> 6, dh = n & 63;
            int b = row0 >> 10;  // 128-row block spans a single batch
            int s0 = (row0 & 1023) + mbase;
            bf16_t* dst = oVt + ((size_t)((b * HH + h) * DH + dh)) * SS + s0;
#pragma unroll
            for (int mm = 0; mm < 64; mm += 8) {
                bf16x8 v;
#pragma unroll
                for (int e = 0; e < 8; ++e) v[e] = tsm[(mbase + mm + e) * 128 + nloc];
                *(bf16x8*)(dst + mm) = v;
            }
        }
    } else {
        int b = row0 >> 10;
        int len = seq_lens[b];
#pragma unroll
        for (int i = 0; i < 4; ++i) {
            int mrow = row0 + wm + i * 16 + g * 4;
#pragma unroll
            for (int j = 0; j < 4; ++j) {
                int n = col0 + wn + j * 16 + lr;
                float bias = bo[n];
#pragma unroll
                for (int r = 0; r < 4; ++r) {
                    int m = mrow + r;
                    int s = m & 1023;
                    oO[(size_t)m * DD + n] = (s < len) ? (acc[i][j][r] + bias) : 0.f;
                }
            }
        }
    }
}

// ---------------- fused flash attention (persistent, pipelined) ---------------
// 768 persistent blocks x 4 waves pull (b,h,qt) items from a global cursor.
// 3 LDS buffers, counted vmcnt + raw barrier: one barrier/kt, stage(kt+2) in
// flight during compute(kt) -> no vmcnt(0) drain in steady state.
__global__ __launch_bounds__(256) void attn_k(const bf16_t* __restrict__ Q,
                                              const bf16_t* __restrict__ K,
                                              const bf16_t* __restrict__ Vt,
                                              bf16_t* __restrict__ O,
                                              const int* __restrict__ seq_lens,
                                              const ushort* __restrict__ items,
                                              int* __restrict__ meta) {
    __shared__ __align__(16) char smem[49152];  // 3 bufs x (K 8KB + V 8KB)
    __shared__ int s_item;
    const int tid = threadIdx.x, l = tid & 63, w = tid >> 6;
    const int lr = l & 15, g = l >> 4;
    const int nitems = meta[0];
    int* cursor = meta + 1;

    // hoisted swizzled LDS offsets: frag chunk addrs, kt/nt-invariant
    const int x0 = lr * 128 + ((g & 1) << 3);
    const int xr = lr & 7;
    const int a00 = x0 + ((((g >> 1) + 0) ^ xr) << 4);
    const int a01 = x0 + ((((g >> 1) + 2) ^ xr) << 4);
    const int a10 = x0 + ((((g >> 1) + 4) ^ xr) << 4);
    const int a11 = x0 + ((((g >> 1) + 6) ^ xr) << 4);

    for (;;) {
        if (tid == 0) s_item = atomicAdd(cursor, 1);
        __syncthreads();
        const int ii = s_item;
        if (ii >= nitems) return;
        const int itv = items[ii];
        const int qt = itv & 7, bh = itv >> 3;
        const int b = bh >> 3;
        const int len = seq_lens[b];
        const int q0 = qt * 128;
        const int h = bh & 7;

        const bf16_t* kbase = K + (size_t)bh * SS * DH;
        const bf16_t* vbase = Vt + (size_t)bh * DH * SS;

        // Q fragments (B-operand: lane holds col q=lr, rows d=16*(j>>2)+4g+(j&3))
        bf16x8 bq[2][2];
#pragma unroll
        for (int qs = 0; qs < 2; ++qs) {
            const bf16_t* qp = Q + ((size_t)bh * SS + q0 + w * 32 + qs * 16 + lr) * DH;
#pragma unroll
            for (int kk = 0; kk < 2; ++kk) {
                bf16x4 lo = *(const bf16x4*)(qp + kk * 32 + 4 * g);
                bf16x4 hi = *(const bf16x4*)(qp + kk * 32 + 16 + 4 * g);
                bq[qs][kk] = __builtin_shufflevector(lo, hi, 0, 1, 2, 3, 4, 5, 6, 7);
            }
        }

        f32x4 oacc[2][4] = {};              // [qsub][dt]; rows q=4g+r, col dh=lr
        float mrun[2] = {-1e30f, -1e30f};
        float lpart[2] = {0.f, 0.f};

        const int nkt = (len + 63) >> 6;

        auto stage = [&](int buf, int key0) {
            char* smK = smem + buf * 16384;
            char* smV = smK + 8192;
#pragma unroll
            for (int it = 0; it < 2; ++it) {
                int cl = it * 256 + tid;
                int m = cl >> 3, p = cl & 7, c = p ^ (m & 7);
                async_cp16(kbase + (size_t)(key0 + m) * DH + c * 8, smK + cl * 16);
            }
#pragma unroll
            for (int it = 0; it < 2; ++it) {
                int cl = it * 256 + tid;
                int m = cl >> 3, p = cl & 7, c = p ^ (m & 7);
                async_cp16(vbase + (size_t)m * SS + key0 + c * 8, smV + cl * 16);
            }
        };

        stage(0, 0);
        if (nkt > 1) stage(1, 64);
        int cur = 0;

        for (int kt = 0; kt < nkt; ++kt) {
            const int key0 = kt * 64;
            // counted wait: ensure stage(kt) landed; keep stage(kt+1) in flight
            if (kt + 1 < nkt) {
                asm volatile("s_waitcnt vmcnt(4)" ::: "memory");
            } else {
                asm volatile("s_waitcnt vmcnt(0)" ::: "memory");
            }
            __builtin_amdgcn_s_barrier();
            __builtin_amdgcn_sched_barrier(0);
            if (kt + 2 < nkt) {
                int b2 = (cur >= 1) ? cur - 1 : 2;   // (cur+2)%3
                stage(b2, key0 + 128);
            }
            const char* smK = smem + cur * 16384;
            const char* smV = smK + 8192;

            // QK^T (swapped): pacc[qs][nt] rows k=nt*16+4g+r, col q=lr
            f32x4 pacc[2][4] = {};
#pragma unroll
            for (int nt = 0; nt < 4; ++nt) {
                bf16x8 ak0 = frag_at(smK + nt * 2048, a00, a01);
                bf16x8 ak1 = frag_at(smK + nt * 2048, a10, a11);
#pragma unroll
                for (int qs = 0; qs < 2; ++qs) {
                    pacc[qs][nt] = MFMA16(ak0, bq[qs][0], pacc[qs][nt]);
                    pacc[qs][nt] = MFMA16(ak1, bq[qs][1], pacc[qs][nt]);
                }
            }

            const bool full = (key0 + 64 <= len);  // wave-uniform

#pragma unroll
            for (int qs = 0; qs < 2; ++qs) {
                float mloc = -1e30f;
                if (full) {
#pragma unroll
                    for (int nt = 0; nt < 4; ++nt)
#pragma unroll
                        for (int r = 0; r < 4; ++r) mloc = fmaxf(mloc, pacc[qs][nt][r]);
                } else {
#pragma unroll
                    for (int nt = 0; nt < 4; ++nt)
#pragma unroll
                        for (int r = 0; r < 4; ++r) {
                            int kg = key0 + nt * 16 + 4 * g + r;
                            float s = (kg < len) ? pacc[qs][nt][r] : -1e30f;
                            pacc[qs][nt][r] = s;
                            mloc = fmaxf(mloc, s);
                        }
                }
                mloc = fmaxf(mloc, __shfl_xor(mloc, 16, 64));
                mloc = fmaxf(mloc, __shfl_xor(mloc, 32, 64));

                float mn;
                if (__all(mloc <= mrun[qs])) {
                    mn = mrun[qs];  // corr == 1 exactly
                } else {
                    mn = fmaxf(mrun[qs], mloc);
                    float corr = __builtin_amdgcn_exp2f(mrun[qs] - mn);
                    mrun[qs] = mn;
                    lpart[qs] *= corr;
                    float cb[4];
#pragma unroll
                    for (int r = 0; r < 4; ++r) cb[r] = __shfl(corr, 4 * g + r, 64);
#pragma unroll
                    for (int dt = 0; dt < 4; ++dt)
#pragma unroll
                        for (int r = 0; r < 4; ++r) oacc[qs][dt][r] *= cb[r];
                }

                float ls = 0.f;
#pragma unroll
                for (int nt = 0; nt < 4; ++nt)
#pragma unroll
                    for (int r = 0; r < 4; ++r) {
                        float p = __builtin_amdgcn_exp2f(pacc[qs][nt][r] - mn);
                        pacc[qs][nt][r] = p;
                        ls += p;
                    }
                lpart[qs] += ls;

                bf16x8 pa[2];
#pragma unroll
                for (int kf = 0; kf < 2; ++kf)
#pragma unroll
                    for (int j = 0; j < 8; ++j)
                        pa[kf][j] = (bf16_t)pacc[qs][2 * kf + (j >> 2)][j & 3];
#pragma unroll
                for (int kf = 0; kf < 2; ++kf)
#pragma unroll
                    for (int dt = 0; dt < 4; ++dt) {
                        bf16x8 bv = frag_at(smV + dt * 2048, kf ? a10 : a00,
                                            kf ? a11 : a01);
                        oacc[qs][dt] = MFMA16(pa[kf], bv, oacc[qs][dt]);
                    }
            }
            cur = (cur == 2) ? 0 : cur + 1;
        }

        // epilogue: finish l reduce, normalize, store [token][h*64+dh]
#pragma unroll
        for (int qs = 0; qs < 2; ++qs) {
            float lt = lpart[qs];
            lt += __shfl_xor(lt, 16, 64);
            lt += __shfl_xor(lt, 32, 64);
#pragma unroll
            for (int r = 0; r < 4; ++r) {
                float inv = 1.f / __shfl(lt, 4 * g + r, 64);
                int q = q0 + w * 32 + qs * 16 + 4 * g + r;
                size_t orow = ((size_t)b * SS + q) * DD;
#pragma unroll
                for (int dt = 0; dt < 4; ++dt)
                    O[orow + h * DH + dt * 16 + lr] = (bf16_t)(oacc[qs][dt][r] * inv);
            }
        }
    }
}

extern "C" void kernel_launch(void* const* d_in, const int* in_sizes, int n_in,
                              void* d_out, int out_size, void* d_ws, size_t ws_size,
                              hipStream_t stream) {
    const float* x = (const float*)d_in[0];
    const int* seq_lens = (const int*)d_in[1];
    const float* Wq = (const float*)d_in[2];
    const float* Wk = (const float*)d_in[3];
    const float* Wv = (const float*)d_in[4];
    const float* Wo = (const float*)d_in[5];
    const float* bo = (const float*)d_in[6];
    float* out = (float*)d_out;

    char* ws = (char*)d_ws;
    const size_t SEG = (size_t)NTOK * DD * sizeof(bf16_t);  // 16 MB
    bf16_t* xb = (bf16_t*)ws;          // also reused as attention output 'ab'
    bf16_t* qb = (bf16_t*)(ws + SEG);
    bf16_t* kb = (bf16_t*)(ws + 2 * SEG);
    bf16_t* vtb = (bf16_t*)(ws + 3 * SEG);
    bf16_t* wt = (bf16_t*)(ws + 4 * SEG);
    ushort* items = (ushort*)(ws + 4 * SEG + (size_t)4 * DD * DD * sizeof(bf16_t));
    int* meta = (int*)(items + 1024);
    bf16_t* ab = xb;

    build_q_k<<<dim3(1), dim3(64), 0, stream>>>(seq_lens, items, meta);
    cast_x_k<<<dim3((NTOK * DD / 4) / 256), dim3(256), 0, stream>>>(x, xb, NTOK * DD / 4);
    transpose_w_k<<<dim3(16, 16, 4), dim3(32, 8), 0, stream>>>(Wq, Wk, Wv, Wo, wt);
    gemm_k<0><<<dim3(NTOK / 128, DD / 128, 3), dim3(256), 0, stream>>>(
        xb, wt, qb, kb, vtb, nullptr, nullptr, nullptr);
    attn_k<<<dim3(768), dim3(256), 0, stream>>>(qb, kb, vtb, ab, seq_lens, items, meta);
    gemm_k<2><<<dim3(NTOK / 128, DD / 128, 1), dim3(256), 0, stream>>>(
        ab, wt, nullptr, nullptr, nullptr, out, bo, seq_lens);
}

// Round 6
// 122.608 us; speedup vs baseline: 1.1111x; 1.1111x over previous
//
#include <hip/hip_runtime.h>
#include <hip/hip_bf16.h>

typedef __bf16 bf16_t;
typedef __attribute__((ext_vector_type(4))) __bf16 bf16x4;
typedef __attribute__((ext_vector_type(8))) __bf16 bf16x8;
typedef __attribute__((ext_vector_type(4))) float f32x4;

#define MFMA16(a, b, c) __builtin_amdgcn_mfma_f32_16x16x32_bf16((a), (b), (c), 0, 0, 0)

// ---- constants ----
#define BB 16
#define SS 1024
#define DD 512
#define HH 8
#define DH 64
#define NTOK (BB * SS)          // 16384
#define QSCALE 0.18033688f      // dh^-0.5 * log2(e) folded into Q projection

typedef const __attribute__((address_space(1))) void gas_void;
typedef __attribute__((address_space(3))) void las_void;

__device__ __forceinline__ void async_cp16(const void* g, void* l) {
    __builtin_amdgcn_global_load_lds((gas_void*)g, (las_void*)l, 16, 0, 0);
}

// Load one MFMA A/B fragment from a swizzled [rows][64] bf16 LDS tile
// (used by the GEMM main loop only).
__device__ __forceinline__ bf16x8 frag_ld(const char* sm, int row, int kk, int g) {
    int r7 = row & 7;
    int base = row * 128 + ((g & 1) << 3);
    int c0 = ((kk << 2) + (g >> 1)) ^ r7;
    int c1 = ((kk << 2) + 2 + (g >> 1)) ^ r7;
    bf16x4 lo = *(const bf16x4*)(sm + base + (c0 << 4));
    bf16x4 hi = *(const bf16x4*)(sm + base + (c1 << 4));
    return __builtin_shufflevector(lo, hi, 0, 1, 2, 3, 4, 5, 6, 7);
}

// Lane-linear fragment read from frag-major LDS: one ds_read_b128.
__device__ __forceinline__ bf16x8 fragl(const char* sm, int idx, int l) {
    return *(const bf16x8*)(sm + (idx * 64 + l) * 16);
}

// ---------------- cast x -> bf16 ----------------
__global__ __launch_bounds__(256) void cast_x_k(const float* __restrict__ x,
                                                bf16_t* __restrict__ xb, int n4) {
    int i = blockIdx.x * 256 + threadIdx.x;
    if (i < n4) {
        float4 v = ((const float4*)x)[i];
        bf16x4 o;
        o[0] = (bf16_t)v.x; o[1] = (bf16_t)v.y; o[2] = (bf16_t)v.z; o[3] = (bf16_t)v.w;
        *(bf16x4*)(xb + (size_t)i * 4) = o;
    }
}

// ---------------- transpose + cast weights: Wt[n][k] = W[k][n] ----------------
__global__ __launch_bounds__(256) void transpose_w_k(const float* __restrict__ W0,
                                                     const float* __restrict__ W1,
                                                     const float* __restrict__ W2,
                                                     const float* __restrict__ W3,
                                                     bf16_t* __restrict__ Wt) {
    __shared__ float t[32][33];
    int z = blockIdx.z;
    const float* W = (z == 0) ? W0 : (z == 1) ? W1 : (z == 2) ? W2 : W3;
    bf16_t* out = Wt + (size_t)z * DD * DD;
    int n0 = blockIdx.x * 32, k0 = blockIdx.y * 32;
    int tx = threadIdx.x, ty = threadIdx.y;  // (32, 8)
#pragma unroll
    for (int i = 0; i < 32; i += 8)
        t[ty + i][tx] = W[(size_t)(k0 + ty + i) * DD + n0 + tx];
    __syncthreads();
#pragma unroll
    for (int i = 0; i < 32; i += 8)
        out[(size_t)(n0 + ty + i) * DD + k0 + tx] = (bf16_t)t[tx][ty + i];
}

// ---------------- work-queue builder (1 wave) ----------------
__global__ void build_q_k(const int* __restrict__ sl, ushort* __restrict__ items,
                          int* __restrict__ meta) {
    int l = threadIdx.x;
    __shared__ int s_b[BB], s_cnt[BB], s_start[BB];
    if (l < BB) {
        int len = sl[l];
        int rank = 0;
        for (int j = 0; j < BB; ++j) {
            int lj = sl[j];
            if (lj > len || (lj == len && j < l)) ++rank;
        }
        s_b[rank] = l;
        s_cnt[rank] = ((len + 127) >> 7) * HH;
    }
    __syncthreads();
    if (l < BB) {
        int st = 0;
        for (int j = 0; j < l; ++j) st += s_cnt[j];
        s_start[l] = st;
        if (l == BB - 1) { meta[0] = st + s_cnt[l]; meta[1] = 0; }
    }
    __syncthreads();
    if (l < BB) {
        int b = s_b[l], st = s_start[l], c = s_cnt[l];
        int nqt = c >> 3;
        for (int i = 0; i < c; ++i) {
            int h = i / nqt, qt = i - h * nqt;
            items[st + i] = (ushort)((((b << 3) | h) << 3) | qt);
        }
    }
}

// ---------------- GEMM: C[M,512] = A[M,512] * W (given W^T[n][k]) ----------------
// MODE 0: z selects Q(0)/K(1)/V(2). Outputs are written in MFMA-FRAGMENT-MAJOR
//   layout so attention staging is linear and frag reads are lane-linear b128:
//   Qf/Kf chunk[(bh*64+t)*2+kk][lane]: elem j = X[bh][16t+lr][32kk+16(j>>2)+4g+(j&3)]
//   Vf chunk[((bh*16+st)*4+dt)*2+kk][lane]: elem j = V[bh][64st+32kk+16(j>>2)+4g+(j&3)][16dt+lr]
// MODE 2: O projection, fp32 out + bias + query mask.
template <int MODE>
__global__ __launch_bounds__(256) void gemm_k(const bf16_t* __restrict__ A,
                                              const bf16_t* __restrict__ WtBase,
                                              bf16_t* __restrict__ oQ,
                                              bf16_t* __restrict__ oK,
                                              bf16_t* __restrict__ oVt,
                                              float* __restrict__ oO,
                                              const float* __restrict__ bo,
                                              const int* __restrict__ seq_lens) {
    __shared__ __align__(16) char smem[32768];
    char* smA = smem;
    char* smB = smem + 16384;
    const int tid = threadIdx.x;
    const int l = tid & 63, w = tid >> 6;
    const int lr = l & 15, g = l >> 4;
    const int bm = blockIdx.x, bn = blockIdx.y;
    const int z = (MODE == 0) ? blockIdx.z : 3;
    const bf16_t* Wt = WtBase + (size_t)z * DD * DD;
    const int row0 = bm * 128;
    const int col0 = bn * 128;
    const int wm = (w >> 1) * 64, wn = (w & 1) * 64;

    f32x4 acc[4][4] = {};

    for (int kt = 0; kt < 8; ++kt) {
        const int k0 = kt * 64;
        __syncthreads();
#pragma unroll
        for (int it = 0; it < 4; ++it) {
            int cl = it * 256 + tid;
            int m = cl >> 3, p = cl & 7, c = p ^ (m & 7);
            async_cp16(A + (size_t)(row0 + m) * DD + k0 + c * 8, smA + cl * 16);
        }
#pragma unroll
        for (int it = 0; it < 4; ++it) {
            int cl = it * 256 + tid;
            int m = cl >> 3, p = cl & 7, c = p ^ (m & 7);
            async_cp16(Wt + (size_t)(col0 + m) * DD + k0 + c * 8, smB + cl * 16);
        }
        __syncthreads();
#pragma unroll
        for (int kk = 0; kk < 2; ++kk) {
            bf16x8 af[4], bfr[4];
#pragma unroll
            for (int i = 0; i < 4; ++i) af[i] = frag_ld(smA, wm + i * 16 + lr, kk, g);
#pragma unroll
            for (int j = 0; j < 4; ++j) bfr[j] = frag_ld(smB, wn + j * 16 + lr, kk, g);
#pragma unroll
            for (int i = 0; i < 4; ++i)
#pragma unroll
                for (int j = 0; j < 4; ++j)
                    acc[i][j] = MFMA16(af[i], bfr[j], acc[i][j]);
        }
    }

    if (MODE == 0) {
        // stage C-tile -> LDS [128 s][128 n] bf16, 16B-chunk XOR swizzle (^ s&7)
        __syncthreads();
        char* tl = smem;
        const float sc = (z == 0) ? QSCALE : 1.f;
#pragma unroll
        for (int i = 0; i < 4; ++i)
#pragma unroll
            for (int j = 0; j < 4; ++j)
#pragma unroll
                for (int r = 0; r < 4; ++r) {
                    int s = wm + i * 16 + g * 4 + r;
                    int n = wn + j * 16 + lr;
                    int nb = 2 * n;
                    int byte = s * 256 + ((((nb >> 4) ^ (s & 7)) << 4) | (nb & 15));
                    *(bf16_t*)(tl + byte) = (bf16_t)(acc[i][j][r] * sc);
                }
        __syncthreads();
        const int b = row0 >> 10, s0 = row0 & 1023;
        if (z < 2) {
            bf16_t* dst = (z == 0) ? oQ : oK;
#pragma unroll
            for (int c8 = 0; c8 < 8; ++c8) {
                int combo = c8 * 4 + w;                 // 0..31
                int kk = combo & 1, t = (combo >> 1) & 7, hl = combo >> 4;
                int s = 16 * t + lr;
                bf16x4 pr[2];
#pragma unroll
                for (int jj = 0; jj < 2; ++jj) {
                    int nb = 128 * hl + 64 * kk + 32 * jj + 8 * g;
                    int byte = s * 256 + ((((nb >> 4) ^ (s & 7)) << 4) | (nb & 15));
                    pr[jj] = *(const bf16x4*)(tl + byte);
                }
                bf16x8 v = __builtin_shufflevector(pr[0], pr[1], 0, 1, 2, 3, 4, 5, 6, 7);
                int bhh = b * 8 + (col0 >> 6) + hl;
                int tg = (s0 >> 4) + t;
                *(bf16x8*)(dst + (((size_t)bhh * 64 + tg) * 2 + kk) * 512 + l * 8) = v;
            }
        } else {
#pragma unroll
            for (int c8 = 0; c8 < 8; ++c8) {
                int combo = c8 * 4 + w;                 // 0..31
                int kk = combo & 1, dt = (combo >> 1) & 3;
                int st = (combo >> 3) & 1, hl = (combo >> 4) & 1;
                bf16x8 v;
#pragma unroll
                for (int j = 0; j < 8; ++j) {
                    int s = 64 * st + 32 * kk + 16 * (j >> 2) + 4 * g + (j & 3);
                    int n = 64 * hl + 16 * dt + lr;
                    int nb = 2 * n;
                    int byte = s * 256 + ((((nb >> 4) ^ (s & 7)) << 4) | (nb & 15));
                    v[j] = *(const bf16_t*)(tl + byte);
                }
                int bhh = b * 8 + (col0 >> 6) + hl;
                int stg = (s0 >> 6) + st;
                *(bf16x8*)(oVt + ((((size_t)bhh * 16 + stg) * 4 + dt) * 2 + kk) * 512 +
                           l * 8) = v;
            }
        }
    } else {
        int b = row0 >> 10;
        int len = seq_lens[b];
#pragma unroll
        for (int i = 0; i < 4; ++i) {
            int mrow = row0 + wm + i * 16 + g * 4;
#pragma unroll
            for (int j = 0; j < 4; ++j) {
                int n = col0 + wn + j * 16 + lr;
                float bias = bo[n];
#pragma unroll
                for (int r = 0; r < 4; ++r) {
                    int m = mrow + r;
                    int s = m & 1023;
                    oO[(size_t)m * DD + n] = (s < len) ? (acc[i][j][r] + bias) : 0.f;
                }
            }
        }
    }
}

// ---------------- fused flash attention (persistent, frag-major K/V) ----------
// 768 persistent blocks x 4 waves pull (b,h,qt) items from a global cursor.
// K/V staged linearly (frag-major global layout); every fragment read is one
// lane-linear ds_read_b128; V-frags hoisted out of the qs loop (qs-invariant).
__global__ __launch_bounds__(256) void attn_k(const bf16_t* __restrict__ Qf,
                                              const bf16_t* __restrict__ Kf,
                                              const bf16_t* __restrict__ Vf,
                                              bf16_t* __restrict__ O,
                                              const int* __restrict__ seq_lens,
                                              const ushort* __restrict__ items,
                                              int* __restrict__ meta) {
    __shared__ __align__(16) char smem[49152];  // 3 bufs x (K 8KB + V 8KB)
    __shared__ int s_item;
    const int tid = threadIdx.x, l = tid & 63, w = tid >> 6;
    const int lr = l & 15, g = l >> 4;
    const int nitems = meta[0];
    int* cursor = meta + 1;

    for (;;) {
        if (tid == 0) s_item = atomicAdd(cursor, 1);
        __syncthreads();
        const int ii = s_item;
        if (ii >= nitems) return;
        const int itv = items[ii];
        const int qt = itv & 7, bh = itv >> 3;
        const int b = bh >> 3;
        const int len = seq_lens[b];
        const int q0 = qt * 128;
        const int h = bh & 7;

        const bf16_t* kfb = Kf + (size_t)bh * 65536;
        const bf16_t* vfb = Vf + (size_t)bh * 65536;

        // Q fragments: lane-linear b128 from frag-major Qf
        bf16x8 bq[2][2];
#pragma unroll
        for (int qs = 0; qs < 2; ++qs) {
            int t = (q0 >> 4) + 2 * w + qs;
#pragma unroll
            for (int kk = 0; kk < 2; ++kk)
                bq[qs][kk] = *(const bf16x8*)(
                    Qf + (((size_t)bh * 64 + t) * 2 + kk) * 512 + l * 8);
        }

        f32x4 oacc[2][4] = {};              // [qsub][dt]; rows q=4g+r, col dh=lr
        float mrun[2] = {-1e30f, -1e30f};
        float lpart[2] = {0.f, 0.f};

        const int nkt = (len + 63) >> 6;

        auto stage = [&](int buf, int kti) {
            char* smK = smem + buf * 16384;
            char* smV = smK + 8192;
            const bf16_t* ks = kfb + kti * 4096;
            const bf16_t* vs = vfb + kti * 4096;
#pragma unroll
            for (int it = 0; it < 2; ++it) {
                int cl = it * 256 + tid;
                async_cp16(ks + cl * 8, smK + cl * 16);
            }
#pragma unroll
            for (int it = 0; it < 2; ++it) {
                int cl = it * 256 + tid;
                async_cp16(vs + cl * 8, smV + cl * 16);
            }
        };

        stage(0, 0);
        if (nkt > 1) stage(1, 1);
        int cur = 0;

        for (int kt = 0; kt < nkt; ++kt) {
            const int key0 = kt * 64;
            if (kt + 1 < nkt) {
                asm volatile("s_waitcnt vmcnt(4)" ::: "memory");
            } else {
                asm volatile("s_waitcnt vmcnt(0)" ::: "memory");
            }
            __builtin_amdgcn_s_barrier();
            __builtin_amdgcn_sched_barrier(0);
            if (kt + 2 < nkt) {
                int b2 = (cur >= 1) ? cur - 1 : 2;   // (cur+2)%3
                stage(b2, kt + 2);
            }
            const char* smK = smem + cur * 16384;
            const char* smV = smK + 8192;

            // V-frags (qs-invariant): 8 lane-linear b128
            bf16x8 bv[4][2];
#pragma unroll
            for (int dt = 0; dt < 4; ++dt)
#pragma unroll
                for (int kk = 0; kk < 2; ++kk)
                    bv[dt][kk] = fragl(smV, dt * 2 + kk, l);

            // QK^T (swapped): pacc[qs][nt] rows k=nt*16+4g+r, col q=lr
            f32x4 pacc[2][4] = {};
#pragma unroll
            for (int nt = 0; nt < 4; ++nt) {
                bf16x8 ak0 = fragl(smK, nt * 2 + 0, l);
                bf16x8 ak1 = fragl(smK, nt * 2 + 1, l);
#pragma unroll
                for (int qs = 0; qs < 2; ++qs) {
                    pacc[qs][nt] = MFMA16(ak0, bq[qs][0], pacc[qs][nt]);
                    pacc[qs][nt] = MFMA16(ak1, bq[qs][1], pacc[qs][nt]);
                }
            }

            const bool full = (key0 + 64 <= len);  // wave-uniform

#pragma unroll
            for (int qs = 0; qs < 2; ++qs) {
                float mloc = -1e30f;
                if (full) {
#pragma unroll
                    for (int nt = 0; nt < 4; ++nt)
#pragma unroll
                        for (int r = 0; r < 4; ++r) mloc = fmaxf(mloc, pacc[qs][nt][r]);
                } else {
#pragma unroll
                    for (int nt = 0; nt < 4; ++nt)
#pragma unroll
                        for (int r = 0; r < 4; ++r) {
                            int kg = key0 + nt * 16 + 4 * g + r;
                            float s = (kg < len) ? pacc[qs][nt][r] : -1e30f;
                            pacc[qs][nt][r] = s;
                            mloc = fmaxf(mloc, s);
                        }
                }
                mloc = fmaxf(mloc, __shfl_xor(mloc, 16, 64));
                mloc = fmaxf(mloc, __shfl_xor(mloc, 32, 64));

                float mn;
                if (__all(mloc <= mrun[qs])) {
                    mn = mrun[qs];  // corr == 1 exactly
                } else {
                    mn = fmaxf(mrun[qs], mloc);
                    float corr = __builtin_amdgcn_exp2f(mrun[qs] - mn);
                    mrun[qs] = mn;
                    lpart[qs] *= corr;
                    float cb[4];
#pragma unroll
                    for (int r = 0; r < 4; ++r) cb[r] = __shfl(corr, 4 * g + r, 64);
#pragma unroll
                    for (int dt = 0; dt < 4; ++dt)
#pragma unroll
                        for (int r = 0; r < 4; ++r) oacc[qs][dt][r] *= cb[r];
                }

                float ls = 0.f;
#pragma unroll
                for (int nt = 0; nt < 4; ++nt)
#pragma unroll
                    for (int r = 0; r < 4; ++r) {
                        float p = __builtin_amdgcn_exp2f(pacc[qs][nt][r] - mn);
                        pacc[qs][nt][r] = p;
                        ls += p;
                    }
                lpart[qs] += ls;

                bf16x8 pa[2];
#pragma unroll
                for (int kf = 0; kf < 2; ++kf)
#pragma unroll
                    for (int j = 0; j < 8; ++j)
                        pa[kf][j] = (bf16_t)pacc[qs][2 * kf + (j >> 2)][j & 3];
#pragma unroll
                for (int kf = 0; kf < 2; ++kf)
#pragma unroll
                    for (int dt = 0; dt < 4; ++dt)
                        oacc[qs][dt] = MFMA16(pa[kf], bv[dt][kf], oacc[qs][dt]);
            }
            cur = (cur == 2) ? 0 : cur + 1;
        }

        // epilogue: finish l reduce, normalize, store [token][h*64+dh]
#pragma unroll
        for (int qs = 0; qs < 2; ++qs) {
            float lt = lpart[qs];
            lt += __shfl_xor(lt, 16, 64);
            lt += __shfl_xor(lt, 32, 64);
#pragma unroll
            for (int r = 0; r < 4; ++r) {
                float inv = 1.f / __shfl(lt, 4 * g + r, 64);
                int q = q0 + w * 32 + qs * 16 + 4 * g + r;
                size_t orow = ((size_t)b * SS + q) * DD;
#pragma unroll
                for (int dt = 0; dt < 4; ++dt)
                    O[orow + h * DH + dt * 16 + lr] = (bf16_t)(oacc[qs][dt][r] * inv);
            }
        }
    }
}

extern "C" void kernel_launch(void* const* d_in, const int* in_sizes, int n_in,
                              void* d_out, int out_size, void* d_ws, size_t ws_size,
                              hipStream_t stream) {
    const float* x = (const float*)d_in[0];
    const int* seq_lens = (const int*)d_in[1];
    const float* Wq = (const float*)d_in[2];
    const float* Wk = (const float*)d_in[3];
    const float* Wv = (const float*)d_in[4];
    const float* Wo = (const float*)d_in[5];
    const float* bo = (const float*)d_in[6];
    float* out = (float*)d_out;

    char* ws = (char*)d_ws;
    const size_t SEG = (size_t)NTOK * DD * sizeof(bf16_t);  // 16 MB
    bf16_t* xb = (bf16_t*)ws;          // also reused as attention output 'ab'
    bf16_t* qb = (bf16_t*)(ws + SEG);
    bf16_t* kb = (bf16_t*)(ws + 2 * SEG);
    bf16_t* vtb = (bf16_t*)(ws + 3 * SEG);
    bf16_t* wt = (bf16_t*)(ws + 4 * SEG);
    ushort* items = (ushort*)(ws + 4 * SEG + (size_t)4 * DD * DD * sizeof(bf16_t));
    int* meta = (int*)(items + 1024);
    bf16_t* ab = xb;

    build_q_k<<<dim3(1), dim3(64), 0, stream>>>(seq_lens, items, meta);
    cast_x_k<<<dim3((NTOK * DD / 4) / 256), dim3(256), 0, stream>>>(x, xb, NTOK * DD / 4);
    transpose_w_k<<<dim3(16, 16, 4), dim3(32, 8), 0, stream>>>(Wq, Wk, Wv, Wo, wt);
    gemm_k<0><<<dim3(NTOK / 128, DD / 128, 3), dim3(256), 0, stream>>>(
        xb, wt, qb, kb, vtb, nullptr, nullptr, nullptr);
    attn_k<<<dim3(768), dim3(256), 0, stream>>>(qb, kb, vtb, ab, seq_lens, items, meta);
    gemm_k<2><<<dim3(NTOK / 128, DD / 128, 1), dim3(256), 0, stream>>>(
        ab, wt, nullptr, nullptr, nullptr, out, bo, seq_lens);
}